// Round 10
// baseline (391.002 us; speedup 1.0000x reference)
//
#include <hip/hip_runtime.h>
#include <hip/hip_bf16.h>
#include <math.h>

// ---------------------------------------------------------------------------
// WindowAttention (self + mutual), MI355X / gfx950.
// R14 = R12's fused body (harness-verified numerics) with __launch_bounds__
// (512,4) instead of (512,6), + R13's tile-transpose prep.
// Register-budget law (measured R10-R13): (512,2)->128, (512,4)->64,
// (512,6)->40 regs. R12's 53,760B LDS reached 3 blocks/CU (occupancy 56.7%
// on its one clean dispatch) but the 40-reg budget caused a spill storm.
// (512,4) keeps the proven 64-reg allocation while LDS caps residency at
// 3 blocks/CU (163,840/53,760 = 3.04) -> 24 waves/CU vs R13's 16.
//   - wbuf stages Q/K only (24,576B); V-proj direct-global double-buffered
//   - qs [16][40]: P staged in two 32-key batches
//   - epilogue: 6 x 64-K W_proj chunks ([192][64] x2 overlay)
// ---------------------------------------------------------------------------

#define SCALE_F 0.17677669529663687f   // 32^-0.5
#define LOG2E_F 1.4426950408889634f

// ws layout (bytes)
#define WS_WQKV_T   0u        // [6 ks][576 col][32 k] bf16 (Q-cols ×SCALE×LOG2E)
#define WS_WQKVM_T  221184u   // [6 ks][576 col][32 k] bf16
#define WS_WPROJ_T  442368u   // [192 n][384 k] bf16 (W_proj^T)
#define WS_RPBG     589824u   // [6][128][half*64 + l16*4 + j] bf16, ×LOG2E
#define WS_NEEDED   786432u

typedef __bf16 bf16x8 __attribute__((ext_vector_type(8)));
typedef __bf16 bf16x4 __attribute__((ext_vector_type(4)));
typedef float  f32x4  __attribute__((ext_vector_type(4)));

#define MFMA(a, b, c) __builtin_amdgcn_mfma_f32_16x16x32_bf16((a), (b), (c), 0, 0, 0)

#if __has_builtin(__builtin_amdgcn_exp2f)
#define EXP2(x) __builtin_amdgcn_exp2f(x)
#else
#define EXP2(x) exp2f(x)
#endif
#if __has_builtin(__builtin_amdgcn_rcpf)
#define RCP(x) __builtin_amdgcn_rcpf(x)
#else
#define RCP(x) (1.0f / (x))
#endif

// direct global -> LDS DMA, 16B per lane; LDS dest = wave-uniform base +
// lane*16 (linear), global source is per-lane.
#define GLOAD_LDS(gp, lp)                                                   \
    __builtin_amdgcn_global_load_lds(                                       \
        (const __attribute__((address_space(1))) unsigned int*)(gp),        \
        (__attribute__((address_space(3))) unsigned int*)(lp), 16, 0, 0)

// ---------------------------------------------------------------------------
// prep: LDS tile transposes for the weight tables + rpbg gather.
// grid = 456 x 256: blocks 0..53 qkv tiles (32k x 64col, both matrices),
// 54..71 wproj tiles (64k x 64n), 72..455 rpbg gather.
__global__ void prep_kernel(const float* __restrict__ w_qkv,
                            const float* __restrict__ w_qkvm,
                            const float* __restrict__ w_proj,
                            const float* __restrict__ rpb_table,
                            const int*   __restrict__ rel_idx,
                            char* __restrict__ ws) {
    __shared__ __bf16 tb[64][73];
    const int blk = blockIdx.x;
    const int tid = threadIdx.x;

    if (blk < 54) {                    // wqkv_t / wqkvm_t: [ks][col][32]
        const int tk = blk / 9, tc = blk - tk * 9;
        const int k0 = tk * 32, c0 = tc * 64;
        #pragma unroll 1
        for (int m = 0; m < 2; ++m) {
            const float* src = m ? w_qkvm : w_qkv;
            __bf16* dst = (__bf16*)(ws + (m ? WS_WQKVM_T : WS_WQKV_T));
            #pragma unroll
            for (int i = 0; i < 8; ++i) {            // coalesced 256B rows
                const int r  = (tid >> 6) + i * 4;   // 0..31
                const int cl = tid & 63;
                const int gc = c0 + cl;
                const float sc = (gc < 192) ? SCALE_F * LOG2E_F : 1.0f;
                tb[r][cl] = (__bf16)(src[(k0 + r) * 576 + gc] * sc);
            }
            __syncthreads();
            {                                        // coalesced bf16x8 stores
                const int cl  = tid >> 2;            // 0..63
                const int kl0 = (tid & 3) * 8;       // 0..24
                bf16x8 v;
                #pragma unroll
                for (int j = 0; j < 8; ++j) v[j] = tb[kl0 + j][cl];
                *(bf16x8*)&dst[tk * 18432 + (c0 + cl) * 32 + kl0] = v;
            }
            __syncthreads();
        }
    } else if (blk < 72) {             // wproj_t: [n][k]
        const int b2 = blk - 54;
        const int tk = b2 / 3, tn = b2 - tk * 3;
        const int k0 = tk * 64, n0 = tn * 64;
        #pragma unroll
        for (int i = 0; i < 16; ++i) {               // coalesced 256B rows
            const int r  = (tid >> 6) + i * 4;       // 0..63
            const int nl = tid & 63;
            tb[r][nl] = (__bf16)w_proj[(k0 + r) * 192 + n0 + nl];
        }
        __syncthreads();
        __bf16* dst = (__bf16*)(ws + WS_WPROJ_T);
        #pragma unroll
        for (int half = 0; half < 2; ++half) {       // coalesced bf16x8 stores
            const int nl  = tid >> 2;                // 0..63
            const int kl0 = (tid & 3) * 8 + half * 32;
            bf16x8 v;
            #pragma unroll
            for (int j = 0; j < 8; ++j) v[j] = tb[kl0 + j][nl];
            *(bf16x8*)&dst[(n0 + nl) * 384 + k0 + kl0] = v;
        }
    } else {                           // rpbg: [h][i][half*64 + l16*4 + j]
        const int o = (blk - 72) * 256 + tid;        // 0..98303
        const int h = o / 16384, r2 = o - h * 16384;
        const int i = r2 >> 7, c = r2 & 127;
        const int half = c >> 6, cc = c & 63;
        const int l16 = cc >> 2, jj = cc & 3;
        const int jcol = l16 + (half * 4 + jj) * 16;
        ((__bf16*)(ws + WS_RPBG))[o] =
            (__bf16)(rpb_table[rel_idx[i * 128 + jcol] * 6 + h] * LOG2E_F);
    }
}

// ---------------------------------------------------------------------------
// Block = window. 512 threads = 8 waves; wave w owns query/out rows
// [16w, 16w+16). MFMA 16x16x32 bf16 layouts (HW-verified):
//   A[m = lane&15][k = quad*8 + j]; B[k = quad*8 + j][n = lane&15]
//   D: col = lane&15, row = quad*4 + reg
// LDS (53,760 B -> 3 blocks/CU at the 64-reg (512,4) budget):
//   attn:  wbuf[12288 el] @0 (Q/K weights, 24x1KB swizzled chunks)
//          kh1[128][40] @24576, vt1[32][136] @34816, qs[8][16][40] @43520
//   epi:   bwA[12288 el] @0, bwB[12288 el] @24576 ([192][64] chunks, overlay)
__global__ __launch_bounds__(512, 4)
void fused_kernel(const float* __restrict__ x,
                  const float* __restrict__ mask,
                  const float* __restrict__ pos_bias,
                  const char*  __restrict__ ws,
                  const float* __restrict__ b_proj,
                  float* __restrict__ out) {
    __shared__ alignas(16) char smem[53760];
    __bf16* wbuf          = (__bf16*)smem;
    __bf16 (*kh1)[40]     = (__bf16(*)[40])(smem + 24576);
    __bf16 (*vt1)[136]    = (__bf16(*)[136])(smem + 34816);
    __bf16 (*qs)[16][40]  = (__bf16(*)[16][40])(smem + 43520);
    __bf16* bwA           = (__bf16*)smem;            // epilogue overlay
    __bf16* bwB           = (__bf16*)(smem + 24576);  // epilogue overlay

    // XCD-bijective swizzle: 8 mask windows per XCD (512KB, L2-resident).
    const int i0  = blockIdx.x;
    const int xcd = i0 & 7;
    const int j0  = i0 >> 3;                 // [0,128)
    const int wm  = (j0 >> 4) * 8 + xcd;     // [0,64)
    const int b   = (j0 & 15) * 64 + wm;     // [0,1024)

    const int tid  = threadIdx.x;
    const int wave = tid >> 6;
    const int lane = tid & 63;
    const int quad = lane >> 4;
    const int l16  = lane & 15;
    const int mrow = wave * 16;

    const __bf16* rpbg = (const __bf16*)(ws + WS_RPBG);
    __bf16* concat = (__bf16*)out;     // bf16 alias; block-exclusive rows
    __bf16 (*qw)[40] = qs[wave];

    // swizzled 16B-slot offsets (elements)
    const int sl8 = (lane ^ ((lane >> 3) & 7)) * 8;            // stage side
    const int spq = l16 * 4 + quad;
    const int sp8 = (spq ^ ((spq >> 3) & 7)) * 8;              // read side

    // ---- stage Q,K weights of head h (24 x 1KB chunks, 3 per wave) ----
    auto stageW = [&](const __bf16* wtb, int h) {
        #pragma unroll
        for (int ii = 0; ii < 3; ++ii) {
            const int i = wave + ii * 8;               // 0..23
            const int p = i / 12, r = i - p * 12;      // p: 0=Q, 1=K
            const int ks = r >> 1, half = r & 1;
            const __bf16* gp = wtb + ks * 18432
                + (p * 192 + h * 32 + half * 16) * 32 + sl8;
            GLOAD_LDS(gp, &wbuf[i * 512]);
        }
    };

    // ---- x rows -> A-fragments (branch1 adds pos_bias) ----
    bf16x8 afrag[6];
    auto loadA = [&](int br) {
        const float* xr = x + (size_t)b * 24576 + (mrow + l16) * 192;
        const float* pr = pos_bias + ((mrow + l16) & 63) * 192;
        #pragma unroll
        for (int ks = 0; ks < 6; ++ks) {
            const int k0 = ks * 32 + quad * 8;
            float4 v0 = *(const float4*)(xr + k0);
            float4 v1 = *(const float4*)(xr + k0 + 4);
            if (br) {
                float4 p0 = *(const float4*)(pr + k0);
                float4 p1 = *(const float4*)(pr + k0 + 4);
                v0.x += p0.x; v0.y += p0.y; v0.z += p0.z; v0.w += p0.w;
                v1.x += p1.x; v1.y += p1.y; v1.z += p1.z; v1.w += p1.w;
            }
            bf16x8 f;
            f[0] = (__bf16)v0.x; f[1] = (__bf16)v0.y;
            f[2] = (__bf16)v0.z; f[3] = (__bf16)v0.w;
            f[4] = (__bf16)v1.x; f[5] = (__bf16)v1.y;
            f[6] = (__bf16)v1.z; f[7] = (__bf16)v1.w;
            afrag[ks] = f;
        }
    };

    // Q/K proj from staged LDS weights (p: 0=Q, 1=K)
    auto runprojQK = [&](int p, f32x4* acc) {
        const int cb = p * 6144;
        #pragma unroll
        for (int ks = 0; ks < 6; ++ks) {
            bf16x8 b0 = *(const bf16x8*)&wbuf[cb + ks * 1024 + sp8];
            bf16x8 b1 = *(const bf16x8*)&wbuf[cb + ks * 1024 + 512 + sp8];
            acc[0] = MFMA(afrag[ks], b0, acc[0]);
            acc[1] = MFMA(afrag[ks], b1, acc[1]);
        }
    };
    // V proj direct from global (double-buffered, coalesced [ks][col][32])
    auto runprojV = [&](const __bf16* wtb, int h, f32x4* acc) {
        const __bf16* wb = wtb + (size_t)(384 + h * 32 + l16) * 32 + quad * 8;
        bf16x8 bA0 = *(const bf16x8*)(wb);
        bf16x8 bA1 = *(const bf16x8*)(wb + 512);
        bf16x8 bB0, bB1;
        #pragma unroll
        for (int ks = 0; ks < 6; ++ks) {
            const __bf16* wn = wb + (size_t)(ks + 1) * 18432;
            if ((ks & 1) == 0) {
                if (ks < 5) { bB0 = *(const bf16x8*)(wn);
                              bB1 = *(const bf16x8*)(wn + 512); }
                acc[0] = MFMA(afrag[ks], bA0, acc[0]);
                acc[1] = MFMA(afrag[ks], bA1, acc[1]);
            } else {
                if (ks < 5) { bA0 = *(const bf16x8*)(wn);
                              bA1 = *(const bf16x8*)(wn + 512); }
                acc[0] = MFMA(afrag[ks], bB0, acc[0]);
                acc[1] = MFMA(afrag[ks], bB1, acc[1]);
            }
        }
    };

    stageW((const __bf16*)(ws + WS_WQKV_T), 0);
    loadA(0);               // overlaps the DMA
    __syncthreads();        // wbuf(0,0) drained

    #pragma unroll 1
    for (int br = 0; br < 2; ++br) {
        const __bf16* wtb = (const __bf16*)(ws + (br ? WS_WQKVM_T : WS_WQKV_T));
        if (br) loadA(1);
        #pragma unroll 1
        for (int h = 0; h < 6; ++h) {
            // ---- K -> kh1 [token][dim] ----
            {
                f32x4 acc[2] = {};
                runprojQK(1, acc);
                #pragma unroll
                for (int nt = 0; nt < 2; ++nt)
                    #pragma unroll
                    for (int r = 0; r < 4; ++r)
                        kh1[mrow + quad * 4 + r][nt * 16 + l16] = (__bf16)acc[nt][r];
            }
            // ---- V -> vt1 [dim][token] (weights direct from global) ----
            {
                f32x4 acc[2] = {};
                runprojV(wtb, h, acc);
                #pragma unroll
                for (int nt = 0; nt < 2; ++nt) {
                    bf16x4 pv;
                    #pragma unroll
                    for (int r = 0; r < 4; ++r) pv[r] = (__bf16)acc[nt][r];
                    *(bf16x4*)&vt1[nt * 16 + l16][mrow + quad * 4] = pv;
                }
            }
            // ---- Q (pre-scaled) -> qw -> A-fragment ----
            bf16x8 aq;
            {
                f32x4 acc[2] = {};
                runprojQK(0, acc);
                #pragma unroll
                for (int nt = 0; nt < 2; ++nt)
                    #pragma unroll
                    for (int r = 0; r < 4; ++r)
                        qw[quad * 4 + r][nt * 16 + l16] = (__bf16)acc[nt][r];
                aq = *(const bf16x8*)&qw[l16][quad * 8];
            }
            __syncthreads();    // (A) K/V visible; wbuf reads of this head done

            // prefetch next (branch, head) Q/K weights under attention
            if (!(br == 1 && h == 5)) {
                const __bf16* nwt = (h == 5)
                    ? (const __bf16*)(ws + WS_WQKVM_T) : wtb;
                stageW(nwt, (h == 5) ? 0 : h + 1);
            }

            f32x4 o0 = {}, o1 = {};
            float rsum[4] = {0.f, 0.f, 0.f, 0.f};

            if (br == 0) {
                const float*  mp = mask + ((size_t)wm * 128 + mrow + quad * 4) * 128 + l16;
                const __bf16* rb = rpbg + ((size_t)(h * 128 + mrow + quad * 4) << 7) + l16 * 4;
                #pragma unroll
                for (int half = 0; half < 2; ++half) {
                    f32x4 s4[4];
                    #pragma unroll
                    for (int r = 0; r < 4; ++r) {
                        bf16x4 rvr = *(const bf16x4*)(rb + r * 128 + half * 64);
                        #pragma unroll
                        for (int j = 0; j < 4; ++j)
                            s4[j][r] = fmaf(mp[r * 128 + (half * 4 + j) * 16],
                                            LOG2E_F, (float)rvr[j]);
                    }
                    #pragma unroll
                    for (int j = 0; j < 4; ++j) {
                        bf16x8 bk = *(const bf16x8*)
                            &kh1[(half * 4 + j) * 16 + l16][quad * 8];
                        s4[j] = MFMA(aq, bk, s4[j]);
                    }
                    #pragma unroll
                    for (int r = 0; r < 4; ++r)
                        #pragma unroll
                        for (int j = 0; j < 4; ++j) {
                            float p = EXP2(s4[j][r]);
                            s4[j][r] = p;
                            rsum[r] += p;
                        }
                    // PV in two 32-key batches (qs is [16][40])
                    #pragma unroll
                    for (int t = 0; t < 2; ++t) {
                        #pragma unroll
                        for (int j = 0; j < 2; ++j)
                            #pragma unroll
                            for (int r = 0; r < 4; ++r)
                                qw[quad * 4 + r][j * 16 + l16] =
                                    (__bf16)s4[t * 2 + j][r];
                        bf16x8 p = *(const bf16x8*)&qw[l16][quad * 8];
                        bf16x8 bv0 = *(const bf16x8*)
                            &vt1[l16][half * 64 + t * 32 + quad * 8];
                        bf16x8 bv1 = *(const bf16x8*)
                            &vt1[16 + l16][half * 64 + t * 32 + quad * 8];
                        o0 = MFMA(p, bv0, o0);
                        o1 = MFMA(p, bv1, o1);
                    }
                }
            } else {
                const int kbase = (mrow < 64) ? 64 : 0;
                const float* mp = mask
                    + ((size_t)wm * 128 + ((mrow + quad * 4) & 63)) * 128 + l16;
                f32x4 s4[4];
                #pragma unroll
                for (int r = 0; r < 4; ++r)
                    #pragma unroll
                    for (int j = 0; j < 4; ++j)
                        s4[j][r] = mp[r * 128 + j * 16] * LOG2E_F;
                #pragma unroll
                for (int j = 0; j < 4; ++j) {
                    bf16x8 bk = *(const bf16x8*)
                        &kh1[kbase + j * 16 + l16][quad * 8];
                    s4[j] = MFMA(aq, bk, s4[j]);
                }
                #pragma unroll
                for (int r = 0; r < 4; ++r)
                    #pragma unroll
                    for (int j = 0; j < 4; ++j) {
                        float p = EXP2(s4[j][r]);
                        s4[j][r] = p;
                        rsum[r] += p;
                    }
                #pragma unroll
                for (int t = 0; t < 2; ++t) {
                    #pragma unroll
                    for (int j = 0; j < 2; ++j)
                        #pragma unroll
                        for (int r = 0; r < 4; ++r)
                            qw[quad * 4 + r][j * 16 + l16] =
                                (__bf16)s4[t * 2 + j][r];
                    bf16x8 p = *(const bf16x8*)&qw[l16][quad * 8];
                    bf16x8 bv0 = *(const bf16x8*)
                        &vt1[l16][kbase + t * 32 + quad * 8];
                    bf16x8 bv1 = *(const bf16x8*)
                        &vt1[16 + l16][kbase + t * 32 + quad * 8];
                    o0 = MFMA(p, bv0, o0);
                    o1 = MFMA(p, bv1, o1);
                }
            }

            float rl[4];
            #pragma unroll
            for (int r = 0; r < 4; ++r) {
                float sum = rsum[r];
                #pragma unroll
                for (int off = 1; off < 16; off <<= 1)
                    sum += __shfl_xor(sum, off, 64);
                rl[r] = RCP(sum);
            }
            __syncthreads();    // (B) kh1/vt1/qs reads done; prefetch drained

            // ---- per-head output: wave 16x32 LDS transpose -> uint4 ----
            #pragma unroll
            for (int r = 0; r < 4; ++r) {
                qw[quad * 4 + r][l16]      = (__bf16)(o0[r] * rl[r]);
                qw[quad * 4 + r][16 + l16] = (__bf16)(o1[r] * rl[r]);
            }
            {
                const int rloc = lane >> 2;
                const int cpart = (lane & 3) * 8;
                uint4 val = *(const uint4*)&qw[rloc][cpart];
                const int grow = mrow + rloc;
                const int rowm = br ? ((grow + 64) & 127) : grow;
                const int colofs = br ? 0 : 192;
                *(uint4*)&concat[((size_t)b * 128 + rowm) * 384 + colofs + h * 32 + cpart] = val;
            }
        }
    }

    // ======== epilogue: out = concat @ w_proj + b_proj (own 128 rows) ======
    __syncthreads();    // concat writes visible block-wide; attn LDS dead

    const __bf16* wp = (const __bf16*)(ws + WS_WPROJ_T);
    const size_t r0 = (size_t)b * 128;

    // stage 64-K chunk c of W_proj^T as [192][64], swizzled 16B slots
    auto stageP = [&](int c, __bf16* buf) {
        #pragma unroll
        for (int ii = 0; ii < 3; ++ii) {
            const int i = wave + ii * 8;              // 0..23
            const int e = i * 512 + sl8;              // logical element
            const int row = e >> 6;
            const int col = e & 63;
            GLOAD_LDS(wp + row * 384 + c * 64 + col, &buf[i * 512]);
        }
    };

    f32x4 acc[12] = {};
    auto computeC = [&](const __bf16* buf, int c) {
        const __bf16* arow = concat + (r0 + mrow + l16) * 384 + c * 64 + quad * 8;
        bf16x8 af0 = *(const bf16x8*)(arow);
        bf16x8 af1 = *(const bf16x8*)(arow + 32);
        #pragma unroll
        for (int k3 = 0; k3 < 2; ++k3) {
            bf16x8 af = k3 ? af1 : af0;
            #pragma unroll
            for (int nt = 0; nt < 12; ++nt) {
                const int s  = (nt * 16 + l16) * 8 + k3 * 4 + quad;
                const int sp = s ^ ((s >> 3) & 7);
                bf16x8 bb = *(const bf16x8*)&buf[sp * 8];
                acc[nt] = MFMA(af, bb, acc[nt]);
            }
        }
    };

    stageP(0, bwA);
    __syncthreads();
    stageP(1, bwB); computeC(bwA, 0);
    __syncthreads();
    stageP(2, bwA); computeC(bwB, 1);
    __syncthreads();
    stageP(3, bwB); computeC(bwA, 2);
    __syncthreads();
    stageP(4, bwA); computeC(bwB, 3);
    __syncthreads();
    stageP(5, bwB); computeC(bwA, 4);
    __syncthreads();
    computeC(bwB, 5);

    #pragma unroll
    for (int nt = 0; nt < 12; ++nt) {
        const int cc = nt * 16 + l16;
        const float bias = b_proj[cc];
        #pragma unroll
        for (int r = 0; r < 4; ++r)
            out[(r0 + mrow + quad * 4 + r) * 192 + cc] = acc[nt][r] + bias;
    }
}

// ---------------------------------------------------------------------------
extern "C" void kernel_launch(void* const* d_in, const int* in_sizes, int n_in,
                              void* d_out, int out_size, void* d_ws, size_t ws_size,
                              hipStream_t stream) {
    const float* x       = (const float*)d_in[0];
    const float* mask    = (const float*)d_in[1];
    const float* w_qkv   = (const float*)d_in[2];
    const float* w_qkvm  = (const float*)d_in[3];
    const float* w_proj  = (const float*)d_in[4];
    const float* b_proj  = (const float*)d_in[5];
    const float* rpb     = (const float*)d_in[6];
    const float* pos_b   = (const float*)d_in[7];
    const int*   rel_idx = (const int*)d_in[8];

    if (ws_size < WS_NEEDED) return;

    char*  ws  = (char*)d_ws;
    float* out = (float*)d_out;

    prep_kernel<<<456, 256, 0, stream>>>(w_qkv, w_qkvm, w_proj, rpb, rel_idx, ws);
    fused_kernel<<<1024, 512, 0, stream>>>(x, mask, pos_b, ws, b_proj, out);
}

// Round 11
// 376.672 us; speedup vs baseline: 1.0380x; 1.0380x over previous
//
#include <hip/hip_runtime.h>
#include <hip/hip_bf16.h>
#include <math.h>

// ---------------------------------------------------------------------------
// WindowAttention (self + mutual), MI355X / gfx950.
// R15 = R13 (best verified: fused 251.7us, total 371.3us) + epilogue chunk-0
// W_proj staging hoisted into the final head's prefetch slot (wbuf/bwA region
// is dead there; DMA drains at the existing barrier B) -> hides one 36KB
// stage and removes one epilogue barrier.
// Resource model (measured R9-R14): unified reg file budgets TOTAL(arch+acc)
// = 512/waves_per_eu: (512,2)->256, (512,4)->128, (512,6)->85. This kernel
// needs ~64 arch + ~45 acc: fits 128 (2 blocks/CU), spills at 85 (R12) ->
// 3-block occupancy is closed. Traffic-for-occupancy fold also loses (R11).
// ---------------------------------------------------------------------------

#define SCALE_F 0.17677669529663687f   // 32^-0.5
#define LOG2E_F 1.4426950408889634f

// ws layout (bytes)
#define WS_WQKV_T   0u        // [6 ks][576 col][32 k] bf16 (Q-cols ×SCALE×LOG2E)
#define WS_WQKVM_T  221184u   // [6 ks][576 col][32 k] bf16
#define WS_WPROJ_T  442368u   // [192 n][384 k] bf16 (W_proj^T)
#define WS_RPBG     589824u   // [6][128][half*64 + l16*4 + j] bf16, ×LOG2E
#define WS_NEEDED   786432u

typedef __bf16 bf16x8 __attribute__((ext_vector_type(8)));
typedef __bf16 bf16x4 __attribute__((ext_vector_type(4)));
typedef float  f32x4  __attribute__((ext_vector_type(4)));

#define MFMA(a, b, c) __builtin_amdgcn_mfma_f32_16x16x32_bf16((a), (b), (c), 0, 0, 0)

#if __has_builtin(__builtin_amdgcn_exp2f)
#define EXP2(x) __builtin_amdgcn_exp2f(x)
#else
#define EXP2(x) exp2f(x)
#endif
#if __has_builtin(__builtin_amdgcn_rcpf)
#define RCP(x) __builtin_amdgcn_rcpf(x)
#else
#define RCP(x) (1.0f / (x))
#endif

// direct global -> LDS DMA, 16B per lane; LDS dest = wave-uniform base +
// lane*16 (linear), global source is per-lane.
#define GLOAD_LDS(gp, lp)                                                   \
    __builtin_amdgcn_global_load_lds(                                       \
        (const __attribute__((address_space(1))) unsigned int*)(gp),        \
        (__attribute__((address_space(3))) unsigned int*)(lp), 16, 0, 0)

// ---------------------------------------------------------------------------
// prep: LDS tile transposes for the weight tables + rpbg gather.
// grid = 456 x 256: blocks 0..53 qkv tiles (32k x 64col, both matrices),
// 54..71 wproj tiles (64k x 64n), 72..455 rpbg gather.
__global__ void prep_kernel(const float* __restrict__ w_qkv,
                            const float* __restrict__ w_qkvm,
                            const float* __restrict__ w_proj,
                            const float* __restrict__ rpb_table,
                            const int*   __restrict__ rel_idx,
                            char* __restrict__ ws) {
    __shared__ __bf16 tb[64][73];
    const int blk = blockIdx.x;
    const int tid = threadIdx.x;

    if (blk < 54) {                    // wqkv_t / wqkvm_t: [ks][col][32]
        const int tk = blk / 9, tc = blk - tk * 9;
        const int k0 = tk * 32, c0 = tc * 64;
        #pragma unroll 1
        for (int m = 0; m < 2; ++m) {
            const float* src = m ? w_qkvm : w_qkv;
            __bf16* dst = (__bf16*)(ws + (m ? WS_WQKVM_T : WS_WQKV_T));
            #pragma unroll
            for (int i = 0; i < 8; ++i) {            // coalesced 256B rows
                const int r  = (tid >> 6) + i * 4;   // 0..31
                const int cl = tid & 63;
                const int gc = c0 + cl;
                const float sc = (gc < 192) ? SCALE_F * LOG2E_F : 1.0f;
                tb[r][cl] = (__bf16)(src[(k0 + r) * 576 + gc] * sc);
            }
            __syncthreads();
            {                                        // coalesced bf16x8 stores
                const int cl  = tid >> 2;            // 0..63
                const int kl0 = (tid & 3) * 8;       // 0..24
                bf16x8 v;
                #pragma unroll
                for (int j = 0; j < 8; ++j) v[j] = tb[kl0 + j][cl];
                *(bf16x8*)&dst[tk * 18432 + (c0 + cl) * 32 + kl0] = v;
            }
            __syncthreads();
        }
    } else if (blk < 72) {             // wproj_t: [n][k]
        const int b2 = blk - 54;
        const int tk = b2 / 3, tn = b2 - tk * 3;
        const int k0 = tk * 64, n0 = tn * 64;
        #pragma unroll
        for (int i = 0; i < 16; ++i) {               // coalesced 256B rows
            const int r  = (tid >> 6) + i * 4;       // 0..63
            const int nl = tid & 63;
            tb[r][nl] = (__bf16)w_proj[(k0 + r) * 192 + n0 + nl];
        }
        __syncthreads();
        __bf16* dst = (__bf16*)(ws + WS_WPROJ_T);
        #pragma unroll
        for (int half = 0; half < 2; ++half) {       // coalesced bf16x8 stores
            const int nl  = tid >> 2;                // 0..63
            const int kl0 = (tid & 3) * 8 + half * 32;
            bf16x8 v;
            #pragma unroll
            for (int j = 0; j < 8; ++j) v[j] = tb[kl0 + j][nl];
            *(bf16x8*)&dst[(n0 + nl) * 384 + k0 + kl0] = v;
        }
    } else {                           // rpbg: [h][i][half*64 + l16*4 + j]
        const int o = (blk - 72) * 256 + tid;        // 0..98303
        const int h = o / 16384, r2 = o - h * 16384;
        const int i = r2 >> 7, c = r2 & 127;
        const int half = c >> 6, cc = c & 63;
        const int l16 = cc >> 2, jj = cc & 3;
        const int jcol = l16 + (half * 4 + jj) * 16;
        ((__bf16*)(ws + WS_RPBG))[o] =
            (__bf16)(rpb_table[rel_idx[i * 128 + jcol] * 6 + h] * LOG2E_F);
    }
}

// ---------------------------------------------------------------------------
// Block = window. 512 threads = 8 waves; wave w owns query/out rows
// [16w, 16w+16). MFMA 16x16x32 bf16 layouts (HW-verified):
//   A[m = lane&15][k = quad*8 + j]; B[k = quad*8 + j][n = lane&15]
//   D: col = lane&15, row = quad*4 + reg
// LDS (74,240 B -> 2 blocks/CU):
//   attn phase:   wbuf[18432 el] @0 (Q/K/V weights of head, 36x1KB swizzled)
//                 kh1[128][40] @36864, vt1[32][136] @47104, qs[8][16][72] @55808
//   epilogue:     bwA[18432 el] @0, bwB[18432 el] @36864 (overlay; bwA chunk0
//                 staged during the final head, wbuf dead there)
__global__ __launch_bounds__(512, 4)
void fused_kernel(const float* __restrict__ x,
                  const float* __restrict__ mask,
                  const float* __restrict__ pos_bias,
                  const char*  __restrict__ ws,
                  const float* __restrict__ b_proj,
                  float* __restrict__ out) {
    __shared__ alignas(16) char smem[74240];
    __bf16* wbuf            = (__bf16*)smem;
    __bf16 (*kh1)[40]       = (__bf16(*)[40])(smem + 36864);
    __bf16 (*vt1)[136]      = (__bf16(*)[136])(smem + 47104);
    __bf16 (*qs)[16][72]    = (__bf16(*)[16][72])(smem + 55808);
    __bf16* bwA             = (__bf16*)smem;            // epilogue overlay
    __bf16* bwB             = (__bf16*)(smem + 36864);  // epilogue overlay

    // XCD-bijective swizzle: 8 mask windows per XCD (512KB, L2-resident).
    const int i0  = blockIdx.x;
    const int xcd = i0 & 7;
    const int j0  = i0 >> 3;                 // [0,128)
    const int wm  = (j0 >> 4) * 8 + xcd;     // [0,64)
    const int b   = (j0 & 15) * 64 + wm;     // [0,1024)

    const int tid  = threadIdx.x;
    const int wave = tid >> 6;
    const int lane = tid & 63;
    const int quad = lane >> 4;
    const int l16  = lane & 15;
    const int mrow = wave * 16;

    const __bf16* rpbg = (const __bf16*)(ws + WS_RPBG);
    const __bf16* wp   = (const __bf16*)(ws + WS_WPROJ_T);
    __bf16* concat = (__bf16*)out;     // bf16 alias; block-exclusive rows
    __bf16 (*qw)[72] = qs[wave];

    // swizzled 16B-slot offsets (elements)
    const int sl8 = (lane ^ ((lane >> 3) & 7)) * 8;            // stage side
    const int spq = l16 * 4 + quad;
    const int sp8 = (spq ^ ((spq >> 3) & 7)) * 8;              // read side

    // ---- stage head h Q/K/V weights (36KB, 36 x 1KB wave-chunks) ----
    auto stageW = [&](const __bf16* wtb, int h) {
        #pragma unroll
        for (int ii = 0; ii < 5; ++ii) {
            const int i = wave + ii * 8;
            if (i < 36) {
                const int p = i / 12, r = i - p * 12;   // p: 0=Q,1=K,2=V
                const int ks = r >> 1, half = r & 1;
                const __bf16* gp = wtb + ks * 18432
                    + (p * 192 + h * 32 + half * 16) * 32 + sl8;
                GLOAD_LDS(gp, &wbuf[i * 512]);
            }
        }
    };
    // ---- stage 96-K chunk c of W_proj^T as [192][96], swizzled slots ----
    auto stageP = [&](int c, __bf16* buf) {
        #pragma unroll
        for (int ii = 0; ii < 5; ++ii) {
            const int i = wave + ii * 8;
            if (i < 36) {
                const int e = i * 512 + sl8;          // logical element
                const int row = e / 96;
                const int col = e - row * 96;
                const __bf16* gp = wp + row * 384 + c * 96 + col;
                GLOAD_LDS(gp, &buf[i * 512]);
            }
        }
    };

    // ---- x rows -> A-fragments (branch1 adds pos_bias) ----
    bf16x8 afrag[6];
    auto loadA = [&](int br) {
        const float* xr = x + (size_t)b * 24576 + (mrow + l16) * 192;
        const float* pr = pos_bias + ((mrow + l16) & 63) * 192;
        #pragma unroll
        for (int ks = 0; ks < 6; ++ks) {
            const int k0 = ks * 32 + quad * 8;
            float4 v0 = *(const float4*)(xr + k0);
            float4 v1 = *(const float4*)(xr + k0 + 4);
            if (br) {
                float4 p0 = *(const float4*)(pr + k0);
                float4 p1 = *(const float4*)(pr + k0 + 4);
                v0.x += p0.x; v0.y += p0.y; v0.z += p0.z; v0.w += p0.w;
                v1.x += p1.x; v1.y += p1.y; v1.z += p1.z; v1.w += p1.w;
            }
            bf16x8 f;
            f[0] = (__bf16)v0.x; f[1] = (__bf16)v0.y;
            f[2] = (__bf16)v0.z; f[3] = (__bf16)v0.w;
            f[4] = (__bf16)v1.x; f[5] = (__bf16)v1.y;
            f[6] = (__bf16)v1.z; f[7] = (__bf16)v1.w;
            afrag[ks] = f;
        }
    };

    // proj from LDS weights: acc[0..1] += x @ W^T  (p: 0=Q, 1=K, 2=V)
    auto runproj2 = [&](int p, f32x4* acc) {
        const int cb = p * 6144;
        #pragma unroll
        for (int ks = 0; ks < 6; ++ks) {
            bf16x8 b0 = *(const bf16x8*)&wbuf[cb + ks * 1024 + sp8];
            bf16x8 b1 = *(const bf16x8*)&wbuf[cb + ks * 1024 + 512 + sp8];
            acc[0] = MFMA(afrag[ks], b0, acc[0]);
            acc[1] = MFMA(afrag[ks], b1, acc[1]);
        }
    };

    stageW((const __bf16*)(ws + WS_WQKV_T), 0);
    loadA(0);               // overlaps the DMA
    __syncthreads();        // wbuf(0,0) drained

    #pragma unroll 1
    for (int br = 0; br < 2; ++br) {
        const __bf16* wtb = (const __bf16*)(ws + (br ? WS_WQKVM_T : WS_WQKV_T));
        if (br) loadA(1);
        #pragma unroll 1
        for (int h = 0; h < 6; ++h) {
            // ---- K -> kh1 [token][dim] ----
            {
                f32x4 acc[2] = {};
                runproj2(1, acc);
                #pragma unroll
                for (int nt = 0; nt < 2; ++nt)
                    #pragma unroll
                    for (int r = 0; r < 4; ++r)
                        kh1[mrow + quad * 4 + r][nt * 16 + l16] = (__bf16)acc[nt][r];
            }
            // ---- V -> vt1 [dim][token] ----
            {
                f32x4 acc[2] = {};
                runproj2(2, acc);
                #pragma unroll
                for (int nt = 0; nt < 2; ++nt) {
                    bf16x4 pv;
                    #pragma unroll
                    for (int r = 0; r < 4; ++r) pv[r] = (__bf16)acc[nt][r];
                    *(bf16x4*)&vt1[nt * 16 + l16][mrow + quad * 4] = pv;
                }
            }
            // ---- Q (pre-scaled) -> qw -> A-fragment ----
            bf16x8 aq;
            {
                f32x4 acc[2] = {};
                runproj2(0, acc);
                #pragma unroll
                for (int nt = 0; nt < 2; ++nt)
                    #pragma unroll
                    for (int r = 0; r < 4; ++r)
                        qw[quad * 4 + r][nt * 16 + l16] = (__bf16)acc[nt][r];
                aq = *(const bf16x8*)&qw[l16][quad * 8];
            }
            __syncthreads();    // (A) K/V visible; wbuf reads of this head done

            // prefetch next (branch, head) Q/K/V weights under attention;
            // final head: prefetch epilogue chunk 0 instead (wbuf dead)
            if (!(br == 1 && h == 5)) {
                const __bf16* nwt = (h == 5)
                    ? (const __bf16*)(ws + WS_WQKVM_T) : wtb;
                stageW(nwt, (h == 5) ? 0 : h + 1);
            } else {
                stageP(0, bwA);
            }

            f32x4 o0 = {}, o1 = {};
            float rsum[4] = {0.f, 0.f, 0.f, 0.f};

            if (br == 0) {
                const float*  mp = mask + ((size_t)wm * 128 + mrow + quad * 4) * 128 + l16;
                const __bf16* rb = rpbg + ((size_t)(h * 128 + mrow + quad * 4) << 7) + l16 * 4;
                #pragma unroll
                for (int half = 0; half < 2; ++half) {
                    f32x4 s4[4];
                    #pragma unroll
                    for (int r = 0; r < 4; ++r) {
                        bf16x4 rvr = *(const bf16x4*)(rb + r * 128 + half * 64);
                        #pragma unroll
                        for (int j = 0; j < 4; ++j)
                            s4[j][r] = fmaf(mp[r * 128 + (half * 4 + j) * 16],
                                            LOG2E_F, (float)rvr[j]);
                    }
                    #pragma unroll
                    for (int j = 0; j < 4; ++j) {
                        bf16x8 bk = *(const bf16x8*)
                            &kh1[(half * 4 + j) * 16 + l16][quad * 8];
                        s4[j] = MFMA(aq, bk, s4[j]);
                    }
                    #pragma unroll
                    for (int r = 0; r < 4; ++r)
                        #pragma unroll
                        for (int j = 0; j < 4; ++j) {
                            float p = EXP2(s4[j][r]);
                            s4[j][r] = p;
                            rsum[r] += p;
                        }
                    #pragma unroll
                    for (int j = 0; j < 4; ++j)
                        #pragma unroll
                        for (int r = 0; r < 4; ++r)
                            qw[quad * 4 + r][j * 16 + l16] = (__bf16)s4[j][r];
                    #pragma unroll
                    for (int kb = 0; kb < 2; ++kb) {
                        bf16x8 p = *(const bf16x8*)&qw[l16][kb * 32 + quad * 8];
                        bf16x8 bv0 = *(const bf16x8*)
                            &vt1[l16][half * 64 + kb * 32 + quad * 8];
                        bf16x8 bv1 = *(const bf16x8*)
                            &vt1[16 + l16][half * 64 + kb * 32 + quad * 8];
                        o0 = MFMA(p, bv0, o0);
                        o1 = MFMA(p, bv1, o1);
                    }
                }
            } else {
                const int kbase = (mrow < 64) ? 64 : 0;
                const float* mp = mask
                    + ((size_t)wm * 128 + ((mrow + quad * 4) & 63)) * 128 + l16;
                f32x4 s4[4];
                #pragma unroll
                for (int r = 0; r < 4; ++r)
                    #pragma unroll
                    for (int j = 0; j < 4; ++j)
                        s4[j][r] = mp[r * 128 + j * 16] * LOG2E_F;
                #pragma unroll
                for (int j = 0; j < 4; ++j) {
                    bf16x8 bk = *(const bf16x8*)
                        &kh1[kbase + j * 16 + l16][quad * 8];
                    s4[j] = MFMA(aq, bk, s4[j]);
                }
                #pragma unroll
                for (int r = 0; r < 4; ++r)
                    #pragma unroll
                    for (int j = 0; j < 4; ++j) {
                        float p = EXP2(s4[j][r]);
                        s4[j][r] = p;
                        rsum[r] += p;
                    }
                #pragma unroll
                for (int j = 0; j < 4; ++j)
                    #pragma unroll
                    for (int r = 0; r < 4; ++r)
                        qw[quad * 4 + r][j * 16 + l16] = (__bf16)s4[j][r];
                #pragma unroll
                for (int kb = 0; kb < 2; ++kb) {
                    bf16x8 p = *(const bf16x8*)&qw[l16][kb * 32 + quad * 8];
                    bf16x8 bv0 = *(const bf16x8*)
                        &vt1[l16][kbase + kb * 32 + quad * 8];
                    bf16x8 bv1 = *(const bf16x8*)
                        &vt1[16 + l16][kbase + kb * 32 + quad * 8];
                    o0 = MFMA(p, bv0, o0);
                    o1 = MFMA(p, bv1, o1);
                }
            }

            float rl[4];
            #pragma unroll
            for (int r = 0; r < 4; ++r) {
                float sum = rsum[r];
                #pragma unroll
                for (int off = 1; off < 16; off <<= 1)
                    sum += __shfl_xor(sum, off, 64);
                rl[r] = RCP(sum);
            }
            __syncthreads();    // (B) kh1/vt1/qs reads done; prefetch drained

            // ---- per-head output: wave 16x32 LDS transpose -> uint4 ----
            #pragma unroll
            for (int r = 0; r < 4; ++r) {
                qw[quad * 4 + r][l16]      = (__bf16)(o0[r] * rl[r]);
                qw[quad * 4 + r][16 + l16] = (__bf16)(o1[r] * rl[r]);
            }
            {
                const int rloc = lane >> 2;
                const int cpart = (lane & 3) * 8;
                uint4 val = *(const uint4*)&qw[rloc][cpart];
                const int grow = mrow + rloc;
                const int rowm = br ? ((grow + 64) & 127) : grow;
                const int colofs = br ? 0 : 192;
                *(uint4*)&concat[((size_t)b * 128 + rowm) * 384 + colofs + h * 32 + cpart] = val;
            }
        }
    }

    // ======== epilogue: out = concat @ w_proj + b_proj (own 128 rows) ======
    __syncthreads();    // concat writes visible; bwA chunk0 already staged

    const size_t r0 = (size_t)b * 128;
    const __bf16* arow = concat + (r0 + mrow + l16) * 384;

    f32x4 acc[12] = {};
    // A-fragments loaded per chunk (3 live regs instead of 12): keeps the
    // epilogue inside the 64-reg budget -> no scratch spill.
    auto computeC = [&](const __bf16* buf, int c) {
        #pragma unroll
        for (int k3 = 0; k3 < 3; ++k3) {
            bf16x8 af = *(const bf16x8*)&arow[(c * 3 + k3) * 32 + quad * 8];
            #pragma unroll
            for (int nt = 0; nt < 12; ++nt) {
                const int s  = l16 * 12 + quad + nt * 192 + k3 * 4;
                const int sp = s ^ ((s >> 3) & 7);
                bf16x8 bb = *(const bf16x8*)&buf[sp * 8];
                acc[nt] = MFMA(af, bb, acc[nt]);
            }
        }
    };

    stageP(1, bwB);
    computeC(bwA, 0);
    __syncthreads();          // bwB ready; bwA free
    stageP(2, bwA);
    computeC(bwB, 1);
    __syncthreads();          // bwA ready; bwB free
    stageP(3, bwB);
    computeC(bwA, 2);
    __syncthreads();          // bwB ready
    computeC(bwB, 3);

    #pragma unroll
    for (int nt = 0; nt < 12; ++nt) {
        const int cc = nt * 16 + l16;
        const float bias = b_proj[cc];
        #pragma unroll
        for (int r = 0; r < 4; ++r)
            out[(r0 + mrow + quad * 4 + r) * 192 + cc] = acc[nt][r] + bias;
    }
}

// ---------------------------------------------------------------------------
extern "C" void kernel_launch(void* const* d_in, const int* in_sizes, int n_in,
                              void* d_out, int out_size, void* d_ws, size_t ws_size,
                              hipStream_t stream) {
    const float* x       = (const float*)d_in[0];
    const float* mask    = (const float*)d_in[1];
    const float* w_qkv   = (const float*)d_in[2];
    const float* w_qkvm  = (const float*)d_in[3];
    const float* w_proj  = (const float*)d_in[4];
    const float* b_proj  = (const float*)d_in[5];
    const float* rpb     = (const float*)d_in[6];
    const float* pos_b   = (const float*)d_in[7];
    const int*   rel_idx = (const int*)d_in[8];

    if (ws_size < WS_NEEDED) return;

    char*  ws  = (char*)d_ws;
    float* out = (float*)d_out;

    prep_kernel<<<456, 256, 0, stream>>>(w_qkv, w_qkvm, w_proj, rpb, rel_idx, ws);
    fused_kernel<<<1024, 512, 0, stream>>>(x, mask, pos_b, ws, b_proj, out);
}

// Round 12
// 365.086 us; speedup vs baseline: 1.0710x; 1.0317x over previous
//
#include <hip/hip_runtime.h>
#include <hip/hip_bf16.h>
#include <math.h>

// ---------------------------------------------------------------------------
// WindowAttention (self + mutual), MI355X / gfx950.
// R16 = R13 (best verified: fused 251.7us, total 371.3us) + s_setprio(1)
// around the two dense MFMA clusters (proj runproj2, epilogue computeC).
// Mechanism (T5): 2 independent blocks/CU sit at different phases of the
// 12-head barrier chain; setprio biases the SIMD issue arbiter toward the
// MFMA-feeding wave while the sibling block's waves issue loads/exp.
// Resource model (measured R9-R15): unified reg budget TOTAL(arch+acc) =
// 512/waves_per_eu; this kernel needs ~64+45 -> fits (512,4)'s 128 at
// 2 blocks/CU; all occupancy/fold/LDS-cut escape paths measured-closed.
// ---------------------------------------------------------------------------

#define SCALE_F 0.17677669529663687f   // 32^-0.5
#define LOG2E_F 1.4426950408889634f

// ws layout (bytes)
#define WS_WQKV_T   0u        // [6 ks][576 col][32 k] bf16 (Q-cols ×SCALE×LOG2E)
#define WS_WQKVM_T  221184u   // [6 ks][576 col][32 k] bf16
#define WS_WPROJ_T  442368u   // [192 n][384 k] bf16 (W_proj^T)
#define WS_RPBG     589824u   // [6][128][half*64 + l16*4 + j] bf16, ×LOG2E
#define WS_NEEDED   786432u

typedef __bf16 bf16x8 __attribute__((ext_vector_type(8)));
typedef __bf16 bf16x4 __attribute__((ext_vector_type(4)));
typedef float  f32x4  __attribute__((ext_vector_type(4)));

#define MFMA(a, b, c) __builtin_amdgcn_mfma_f32_16x16x32_bf16((a), (b), (c), 0, 0, 0)

#if __has_builtin(__builtin_amdgcn_exp2f)
#define EXP2(x) __builtin_amdgcn_exp2f(x)
#else
#define EXP2(x) exp2f(x)
#endif
#if __has_builtin(__builtin_amdgcn_rcpf)
#define RCP(x) __builtin_amdgcn_rcpf(x)
#else
#define RCP(x) (1.0f / (x))
#endif

// direct global -> LDS DMA, 16B per lane; LDS dest = wave-uniform base +
// lane*16 (linear), global source is per-lane.
#define GLOAD_LDS(gp, lp)                                                   \
    __builtin_amdgcn_global_load_lds(                                       \
        (const __attribute__((address_space(1))) unsigned int*)(gp),        \
        (__attribute__((address_space(3))) unsigned int*)(lp), 16, 0, 0)

// ---------------------------------------------------------------------------
// prep: LDS tile transposes for the weight tables + rpbg gather.
// grid = 456 x 256: blocks 0..53 qkv tiles (32k x 64col, both matrices),
// 54..71 wproj tiles (64k x 64n), 72..455 rpbg gather.
__global__ void prep_kernel(const float* __restrict__ w_qkv,
                            const float* __restrict__ w_qkvm,
                            const float* __restrict__ w_proj,
                            const float* __restrict__ rpb_table,
                            const int*   __restrict__ rel_idx,
                            char* __restrict__ ws) {
    __shared__ __bf16 tb[64][73];
    const int blk = blockIdx.x;
    const int tid = threadIdx.x;

    if (blk < 54) {                    // wqkv_t / wqkvm_t: [ks][col][32]
        const int tk = blk / 9, tc = blk - tk * 9;
        const int k0 = tk * 32, c0 = tc * 64;
        #pragma unroll 1
        for (int m = 0; m < 2; ++m) {
            const float* src = m ? w_qkvm : w_qkv;
            __bf16* dst = (__bf16*)(ws + (m ? WS_WQKVM_T : WS_WQKV_T));
            #pragma unroll
            for (int i = 0; i < 8; ++i) {            // coalesced 256B rows
                const int r  = (tid >> 6) + i * 4;   // 0..31
                const int cl = tid & 63;
                const int gc = c0 + cl;
                const float sc = (gc < 192) ? SCALE_F * LOG2E_F : 1.0f;
                tb[r][cl] = (__bf16)(src[(k0 + r) * 576 + gc] * sc);
            }
            __syncthreads();
            {                                        // coalesced bf16x8 stores
                const int cl  = tid >> 2;            // 0..63
                const int kl0 = (tid & 3) * 8;       // 0..24
                bf16x8 v;
                #pragma unroll
                for (int j = 0; j < 8; ++j) v[j] = tb[kl0 + j][cl];
                *(bf16x8*)&dst[tk * 18432 + (c0 + cl) * 32 + kl0] = v;
            }
            __syncthreads();
        }
    } else if (blk < 72) {             // wproj_t: [n][k]
        const int b2 = blk - 54;
        const int tk = b2 / 3, tn = b2 - tk * 3;
        const int k0 = tk * 64, n0 = tn * 64;
        #pragma unroll
        for (int i = 0; i < 16; ++i) {               // coalesced 256B rows
            const int r  = (tid >> 6) + i * 4;       // 0..63
            const int nl = tid & 63;
            tb[r][nl] = (__bf16)w_proj[(k0 + r) * 192 + n0 + nl];
        }
        __syncthreads();
        __bf16* dst = (__bf16*)(ws + WS_WPROJ_T);
        #pragma unroll
        for (int half = 0; half < 2; ++half) {       // coalesced bf16x8 stores
            const int nl  = tid >> 2;                // 0..63
            const int kl0 = (tid & 3) * 8 + half * 32;
            bf16x8 v;
            #pragma unroll
            for (int j = 0; j < 8; ++j) v[j] = tb[kl0 + j][nl];
            *(bf16x8*)&dst[(n0 + nl) * 384 + k0 + kl0] = v;
        }
    } else {                           // rpbg: [h][i][half*64 + l16*4 + j]
        const int o = (blk - 72) * 256 + tid;        // 0..98303
        const int h = o / 16384, r2 = o - h * 16384;
        const int i = r2 >> 7, c = r2 & 127;
        const int half = c >> 6, cc = c & 63;
        const int l16 = cc >> 2, jj = cc & 3;
        const int jcol = l16 + (half * 4 + jj) * 16;
        ((__bf16*)(ws + WS_RPBG))[o] =
            (__bf16)(rpb_table[rel_idx[i * 128 + jcol] * 6 + h] * LOG2E_F);
    }
}

// ---------------------------------------------------------------------------
// Block = window. 512 threads = 8 waves; wave w owns query/out rows
// [16w, 16w+16). MFMA 16x16x32 bf16 layouts (HW-verified):
//   A[m = lane&15][k = quad*8 + j]; B[k = quad*8 + j][n = lane&15]
//   D: col = lane&15, row = quad*4 + reg
// LDS (74,240 B -> 2 blocks/CU):
//   attn phase:   wbuf[18432 el] @0 (Q/K/V weights of head, 36x1KB swizzled)
//                 kh1[128][40] @36864, vt1[32][136] @47104, qs[8][16][72] @55808
//   epilogue:     bwA[18432 el] @0, bwB[18432 el] @36864 (overlay, after barrier)
__global__ __launch_bounds__(512, 4)
void fused_kernel(const float* __restrict__ x,
                  const float* __restrict__ mask,
                  const float* __restrict__ pos_bias,
                  const char*  __restrict__ ws,
                  const float* __restrict__ b_proj,
                  float* __restrict__ out) {
    __shared__ alignas(16) char smem[74240];
    __bf16* wbuf            = (__bf16*)smem;
    __bf16 (*kh1)[40]       = (__bf16(*)[40])(smem + 36864);
    __bf16 (*vt1)[136]      = (__bf16(*)[136])(smem + 47104);
    __bf16 (*qs)[16][72]    = (__bf16(*)[16][72])(smem + 55808);
    __bf16* bwA             = (__bf16*)smem;            // epilogue overlay
    __bf16* bwB             = (__bf16*)(smem + 36864);  // epilogue overlay

    // XCD-bijective swizzle: 8 mask windows per XCD (512KB, L2-resident).
    const int i0  = blockIdx.x;
    const int xcd = i0 & 7;
    const int j0  = i0 >> 3;                 // [0,128)
    const int wm  = (j0 >> 4) * 8 + xcd;     // [0,64)
    const int b   = (j0 & 15) * 64 + wm;     // [0,1024)

    const int tid  = threadIdx.x;
    const int wave = tid >> 6;
    const int lane = tid & 63;
    const int quad = lane >> 4;
    const int l16  = lane & 15;
    const int mrow = wave * 16;

    const __bf16* rpbg = (const __bf16*)(ws + WS_RPBG);
    __bf16* concat = (__bf16*)out;     // bf16 alias; block-exclusive rows
    __bf16 (*qw)[72] = qs[wave];

    // swizzled 16B-slot offsets (elements)
    const int sl8 = (lane ^ ((lane >> 3) & 7)) * 8;            // stage side
    const int spq = l16 * 4 + quad;
    const int sp8 = (spq ^ ((spq >> 3) & 7)) * 8;              // read side

    // ---- stage head h Q/K/V weights (36KB, 36 x 1KB wave-chunks) ----
    auto stageW = [&](const __bf16* wtb, int h) {
        #pragma unroll
        for (int ii = 0; ii < 5; ++ii) {
            const int i = wave + ii * 8;
            if (i < 36) {
                const int p = i / 12, r = i - p * 12;   // p: 0=Q,1=K,2=V
                const int ks = r >> 1, half = r & 1;
                const __bf16* gp = wtb + ks * 18432
                    + (p * 192 + h * 32 + half * 16) * 32 + sl8;
                GLOAD_LDS(gp, &wbuf[i * 512]);
            }
        }
    };

    // ---- x rows -> A-fragments (branch1 adds pos_bias) ----
    bf16x8 afrag[6];
    auto loadA = [&](int br) {
        const float* xr = x + (size_t)b * 24576 + (mrow + l16) * 192;
        const float* pr = pos_bias + ((mrow + l16) & 63) * 192;
        #pragma unroll
        for (int ks = 0; ks < 6; ++ks) {
            const int k0 = ks * 32 + quad * 8;
            float4 v0 = *(const float4*)(xr + k0);
            float4 v1 = *(const float4*)(xr + k0 + 4);
            if (br) {
                float4 p0 = *(const float4*)(pr + k0);
                float4 p1 = *(const float4*)(pr + k0 + 4);
                v0.x += p0.x; v0.y += p0.y; v0.z += p0.z; v0.w += p0.w;
                v1.x += p1.x; v1.y += p1.y; v1.z += p1.z; v1.w += p1.w;
            }
            bf16x8 f;
            f[0] = (__bf16)v0.x; f[1] = (__bf16)v0.y;
            f[2] = (__bf16)v0.z; f[3] = (__bf16)v0.w;
            f[4] = (__bf16)v1.x; f[5] = (__bf16)v1.y;
            f[6] = (__bf16)v1.z; f[7] = (__bf16)v1.w;
            afrag[ks] = f;
        }
    };

    // proj from LDS weights: acc[0..1] += x @ W^T  (p: 0=Q, 1=K, 2=V)
    // T5: setprio(1) across the 12-MFMA cluster — the sibling block's waves
    // are typically in the load/exp attention phase; bias issue toward MFMA.
    auto runproj2 = [&](int p, f32x4* acc) {
        const int cb = p * 6144;
        __builtin_amdgcn_s_setprio(1);
        #pragma unroll
        for (int ks = 0; ks < 6; ++ks) {
            bf16x8 b0 = *(const bf16x8*)&wbuf[cb + ks * 1024 + sp8];
            bf16x8 b1 = *(const bf16x8*)&wbuf[cb + ks * 1024 + 512 + sp8];
            acc[0] = MFMA(afrag[ks], b0, acc[0]);
            acc[1] = MFMA(afrag[ks], b1, acc[1]);
        }
        __builtin_amdgcn_s_setprio(0);
    };

    stageW((const __bf16*)(ws + WS_WQKV_T), 0);
    loadA(0);               // overlaps the DMA
    __syncthreads();        // wbuf(0,0) drained

    #pragma unroll 1
    for (int br = 0; br < 2; ++br) {
        const __bf16* wtb = (const __bf16*)(ws + (br ? WS_WQKVM_T : WS_WQKV_T));
        if (br) loadA(1);
        #pragma unroll 1
        for (int h = 0; h < 6; ++h) {
            // ---- K -> kh1 [token][dim] ----
            {
                f32x4 acc[2] = {};
                runproj2(1, acc);
                #pragma unroll
                for (int nt = 0; nt < 2; ++nt)
                    #pragma unroll
                    for (int r = 0; r < 4; ++r)
                        kh1[mrow + quad * 4 + r][nt * 16 + l16] = (__bf16)acc[nt][r];
            }
            // ---- V -> vt1 [dim][token] ----
            {
                f32x4 acc[2] = {};
                runproj2(2, acc);
                #pragma unroll
                for (int nt = 0; nt < 2; ++nt) {
                    bf16x4 pv;
                    #pragma unroll
                    for (int r = 0; r < 4; ++r) pv[r] = (__bf16)acc[nt][r];
                    *(bf16x4*)&vt1[nt * 16 + l16][mrow + quad * 4] = pv;
                }
            }
            // ---- Q (pre-scaled) -> qw -> A-fragment ----
            bf16x8 aq;
            {
                f32x4 acc[2] = {};
                runproj2(0, acc);
                #pragma unroll
                for (int nt = 0; nt < 2; ++nt)
                    #pragma unroll
                    for (int r = 0; r < 4; ++r)
                        qw[quad * 4 + r][nt * 16 + l16] = (__bf16)acc[nt][r];
                aq = *(const bf16x8*)&qw[l16][quad * 8];
            }
            __syncthreads();    // (A) K/V visible; wbuf reads of this head done

            // prefetch next (branch, head) Q/K/V weights under attention
            if (!(br == 1 && h == 5)) {
                const __bf16* nwt = (h == 5)
                    ? (const __bf16*)(ws + WS_WQKVM_T) : wtb;
                stageW(nwt, (h == 5) ? 0 : h + 1);
            }

            f32x4 o0 = {}, o1 = {};
            float rsum[4] = {0.f, 0.f, 0.f, 0.f};

            if (br == 0) {
                const float*  mp = mask + ((size_t)wm * 128 + mrow + quad * 4) * 128 + l16;
                const __bf16* rb = rpbg + ((size_t)(h * 128 + mrow + quad * 4) << 7) + l16 * 4;
                #pragma unroll
                for (int half = 0; half < 2; ++half) {
                    f32x4 s4[4];
                    #pragma unroll
                    for (int r = 0; r < 4; ++r) {
                        bf16x4 rvr = *(const bf16x4*)(rb + r * 128 + half * 64);
                        #pragma unroll
                        for (int j = 0; j < 4; ++j)
                            s4[j][r] = fmaf(mp[r * 128 + (half * 4 + j) * 16],
                                            LOG2E_F, (float)rvr[j]);
                    }
                    #pragma unroll
                    for (int j = 0; j < 4; ++j) {
                        bf16x8 bk = *(const bf16x8*)
                            &kh1[(half * 4 + j) * 16 + l16][quad * 8];
                        s4[j] = MFMA(aq, bk, s4[j]);
                    }
                    #pragma unroll
                    for (int r = 0; r < 4; ++r)
                        #pragma unroll
                        for (int j = 0; j < 4; ++j) {
                            float p = EXP2(s4[j][r]);
                            s4[j][r] = p;
                            rsum[r] += p;
                        }
                    #pragma unroll
                    for (int j = 0; j < 4; ++j)
                        #pragma unroll
                        for (int r = 0; r < 4; ++r)
                            qw[quad * 4 + r][j * 16 + l16] = (__bf16)s4[j][r];
                    #pragma unroll
                    for (int kb = 0; kb < 2; ++kb) {
                        bf16x8 p = *(const bf16x8*)&qw[l16][kb * 32 + quad * 8];
                        bf16x8 bv0 = *(const bf16x8*)
                            &vt1[l16][half * 64 + kb * 32 + quad * 8];
                        bf16x8 bv1 = *(const bf16x8*)
                            &vt1[16 + l16][half * 64 + kb * 32 + quad * 8];
                        o0 = MFMA(p, bv0, o0);
                        o1 = MFMA(p, bv1, o1);
                    }
                }
            } else {
                const int kbase = (mrow < 64) ? 64 : 0;
                const float* mp = mask
                    + ((size_t)wm * 128 + ((mrow + quad * 4) & 63)) * 128 + l16;
                f32x4 s4[4];
                #pragma unroll
                for (int r = 0; r < 4; ++r)
                    #pragma unroll
                    for (int j = 0; j < 4; ++j)
                        s4[j][r] = mp[r * 128 + j * 16] * LOG2E_F;
                #pragma unroll
                for (int j = 0; j < 4; ++j) {
                    bf16x8 bk = *(const bf16x8*)
                        &kh1[kbase + j * 16 + l16][quad * 8];
                    s4[j] = MFMA(aq, bk, s4[j]);
                }
                #pragma unroll
                for (int r = 0; r < 4; ++r)
                    #pragma unroll
                    for (int j = 0; j < 4; ++j) {
                        float p = EXP2(s4[j][r]);
                        s4[j][r] = p;
                        rsum[r] += p;
                    }
                #pragma unroll
                for (int j = 0; j < 4; ++j)
                    #pragma unroll
                    for (int r = 0; r < 4; ++r)
                        qw[quad * 4 + r][j * 16 + l16] = (__bf16)s4[j][r];
                #pragma unroll
                for (int kb = 0; kb < 2; ++kb) {
                    bf16x8 p = *(const bf16x8*)&qw[l16][kb * 32 + quad * 8];
                    bf16x8 bv0 = *(const bf16x8*)
                        &vt1[l16][kbase + kb * 32 + quad * 8];
                    bf16x8 bv1 = *(const bf16x8*)
                        &vt1[16 + l16][kbase + kb * 32 + quad * 8];
                    o0 = MFMA(p, bv0, o0);
                    o1 = MFMA(p, bv1, o1);
                }
            }

            float rl[4];
            #pragma unroll
            for (int r = 0; r < 4; ++r) {
                float sum = rsum[r];
                #pragma unroll
                for (int off = 1; off < 16; off <<= 1)
                    sum += __shfl_xor(sum, off, 64);
                rl[r] = RCP(sum);
            }
            __syncthreads();    // (B) kh1/vt1/qs reads done; prefetch drained

            // ---- per-head output: wave 16x32 LDS transpose -> uint4 ----
            #pragma unroll
            for (int r = 0; r < 4; ++r) {
                qw[quad * 4 + r][l16]      = (__bf16)(o0[r] * rl[r]);
                qw[quad * 4 + r][16 + l16] = (__bf16)(o1[r] * rl[r]);
            }
            {
                const int rloc = lane >> 2;
                const int cpart = (lane & 3) * 8;
                uint4 val = *(const uint4*)&qw[rloc][cpart];
                const int grow = mrow + rloc;
                const int rowm = br ? ((grow + 64) & 127) : grow;
                const int colofs = br ? 0 : 192;
                *(uint4*)&concat[((size_t)b * 128 + rowm) * 384 + colofs + h * 32 + cpart] = val;
            }
        }
    }

    // ======== epilogue: out = concat @ w_proj + b_proj (own 128 rows) ======
    __syncthreads();    // concat writes visible block-wide; attn LDS dead

    const __bf16* wp = (const __bf16*)(ws + WS_WPROJ_T);
    const size_t r0 = (size_t)b * 128;
    const __bf16* arow = concat + (r0 + mrow + l16) * 384;

    auto stageP = [&](int c, __bf16* buf) {
        #pragma unroll
        for (int ii = 0; ii < 5; ++ii) {
            const int i = wave + ii * 8;
            if (i < 36) {
                const int e = i * 512 + sl8;          // logical element
                const int row = e / 96;
                const int col = e - row * 96;
                const __bf16* gp = wp + row * 384 + c * 96 + col;
                GLOAD_LDS(gp, &buf[i * 512]);
            }
        }
    };

    f32x4 acc[12] = {};
    // A-fragments loaded per chunk (3 live regs instead of 12): keeps the
    // epilogue inside the 64-reg budget -> no scratch spill.
    auto computeC = [&](const __bf16* buf, int c) {
        __builtin_amdgcn_s_setprio(1);
        #pragma unroll
        for (int k3 = 0; k3 < 3; ++k3) {
            bf16x8 af = *(const bf16x8*)&arow[(c * 3 + k3) * 32 + quad * 8];
            #pragma unroll
            for (int nt = 0; nt < 12; ++nt) {
                const int s  = l16 * 12 + quad + nt * 192 + k3 * 4;
                const int sp = s ^ ((s >> 3) & 7);
                bf16x8 bb = *(const bf16x8*)&buf[sp * 8];
                acc[nt] = MFMA(af, bb, acc[nt]);
            }
        }
        __builtin_amdgcn_s_setprio(0);
    };

    stageP(0, bwA);
    __syncthreads();          // bwA ready
    stageP(1, bwB);
    computeC(bwA, 0);
    __syncthreads();          // bwB ready; bwA free
    stageP(2, bwA);
    computeC(bwB, 1);
    __syncthreads();          // bwA ready; bwB free
    stageP(3, bwB);
    computeC(bwA, 2);
    __syncthreads();          // bwB ready
    computeC(bwB, 3);

    #pragma unroll
    for (int nt = 0; nt < 12; ++nt) {
        const int cc = nt * 16 + l16;
        const float bias = b_proj[cc];
        #pragma unroll
        for (int r = 0; r < 4; ++r)
            out[(r0 + mrow + quad * 4 + r) * 192 + cc] = acc[nt][r] + bias;
    }
}

// ---------------------------------------------------------------------------
extern "C" void kernel_launch(void* const* d_in, const int* in_sizes, int n_in,
                              void* d_out, int out_size, void* d_ws, size_t ws_size,
                              hipStream_t stream) {
    const float* x       = (const float*)d_in[0];
    const float* mask    = (const float*)d_in[1];
    const float* w_qkv   = (const float*)d_in[2];
    const float* w_qkvm  = (const float*)d_in[3];
    const float* w_proj  = (const float*)d_in[4];
    const float* b_proj  = (const float*)d_in[5];
    const float* rpb     = (const float*)d_in[6];
    const float* pos_b   = (const float*)d_in[7];
    const int*   rel_idx = (const int*)d_in[8];

    if (ws_size < WS_NEEDED) return;

    char*  ws  = (char*)d_ws;
    float* out = (float*)d_out;

    prep_kernel<<<456, 256, 0, stream>>>(w_qkv, w_qkvm, w_proj, rpb, rel_idx, ws);
    fused_kernel<<<1024, 512, 0, stream>>>(x, mask, pos_b, ws, b_proj, out);
}